// Round 3
// baseline (365.854 us; speedup 1.0000x reference)
//
#include <hip/hip_runtime.h>
#include <math.h>

#define LQ 2048
#define DM 1024
#define NH 16
#define DH 64
#define UU 38
#define NBH 64            // B*NH = 4*16
#define SCALE 0.125f      // 1/sqrt(64)

typedef _Float16 f16x8 __attribute__((ext_vector_type(8)));
typedef float f32x4 __attribute__((ext_vector_type(4)));

#if __has_builtin(__builtin_amdgcn_exp2f)
#define EXP2F(x) __builtin_amdgcn_exp2f(x)
#else
#define EXP2F(x) exp2f(x)
#endif

// async global->LDS DMA, 16B per lane. LDS dest is wave-uniform base + lane*16.
#define GL2LDS16(gp, lp)                                           \
  __builtin_amdgcn_global_load_lds(                                \
      (const __attribute__((address_space(1))) void*)(gp),         \
      (__attribute__((address_space(3))) void*)(lp), 16, 0, 0)

// ---- workspace layout (bytes), total 40,700,928 (proven to fit in r8) ----
//   lt    : [2][64][2048][2] f64           [0, 4194304)
//   sel   : 64*38 int                       +9728
//   l3    : 64*38 f32 (UNUSED since r9 -- slot kept for layout stability)
//   mask  : [64][2048] s8                   +131072
//   lpart : [64][16][38] f32                +155648 (region 311296)
//   ksp   : [64][32][8192] f16 @ 7146496    (33,554,432 B)
//   opart : [64][16][38][64] f32 ALIASES ksp (9.96 MB; written by attn_pv2
//           strictly after attn_w_mfma's last ksp read -- stream ordered)
#define F_OFF_SEL   4194304
#define F_OFF_L3    4204032
#define F_OFF_MASK  4213760
#define F_OFF_LPART 4344832
#define F_OFF_KSP   7146496
#define F_NEED      40700928ull

// ---------------------------------------------------------------------------
// ksplit: one-time K fp32 -> fp16 hi/lo split with the conflict-free LDS
// image pre-baked (dim-block p stored at p^(k&7)). Read by kl_mfma2 AND
// attn_w_mfma (second read is L2/L3-hot).
// ---------------------------------------------------------------------------
__global__ __launch_bounds__(256) void ksplit_kernel(const float* __restrict__ K,
                                                     _Float16* __restrict__ ksp) {
  int idx = blockIdx.x * 256 + threadIdx.x;   // 1,048,576 total
  int p = idx & 7;
  int k = (idx >> 3) & 63;
  int kc = (idx >> 9) & 31;
  int bh = idx >> 14;
  int b = bh >> 4, h = bh & 15;
  const float* src = K + ((size_t)(b * LQ + kc * 64 + k)) * DM + h * DH + (p ^ (k & 7)) * 8;
  float4 x0 = *(const float4*)src;
  float4 x1 = *(const float4*)(src + 4);
  f16x8 hi, lo;
#define KCV(i, xx) { float x_ = (xx); _Float16 hh = (_Float16)x_; hi[i] = hh; lo[i] = (_Float16)(x_ - (float)hh); }
  KCV(0, x0.x) KCV(1, x0.y) KCV(2, x0.z) KCV(3, x0.w)
  KCV(4, x1.x) KCV(5, x1.y) KCV(6, x1.z) KCV(7, x1.w)
#undef KCV
  _Float16* base = ksp + ((size_t)(bh * 32 + kc)) * 8192;
  *(f16x8*)(base + k * 64 + p * 8) = hi;
  *(f16x8*)(base + 4096 + k * 64 + p * 8) = lo;
}

// ---------------------------------------------------------------------------
// kl_mfma2 r11: 2-WAVE blocks (128 thr), 64 q-rows/block, grid 4096.
// r10 showed staging variants are all ~128-136us: the wall is serialized
// MFMA (45us busy) + VALU (69us busy) with lockstep 4-wave barriers and 29%
// occupancy. 2-wave blocks give ~8 independent barrier domains/CU at
// drifting phases -> cross-wave MFMA/VALU overlap; s_setprio(1) around each
// 6-MFMA cluster (T5 -- pays only with phase diversity, which now exists).
// f64 fold every 128 keys (cadence validated bit-for-bit by r9's pass).
// Numerics otherwise identical: same swizzle, same MFMA chain, f64 totals.
// ---------------------------------------------------------------------------
__global__ __launch_bounds__(128) void kl_mfma2(const float* __restrict__ Q,
                                                const _Float16* __restrict__ ksp,
                                                double* __restrict__ lt) {
  int bh = blockIdx.x & 63;
  int qc = (blockIdx.x >> 6) & 31;    // 32 chunks of 64 q-rows
  int sp = blockIdx.x >> 11;          // 2 key-halves
  int b = bh >> 4, h = bh & 15;
  int t = threadIdx.x;                // 0..127
  int lane = t & 63, w = t >> 6;      // 2 waves
  int quad = lane >> 4, l15 = lane & 15;

  __shared__ __align__(16) _Float16 kbuf[8192];   // 16 KB = 2 x 8 KB dbuf

  f16x8 ahi[2][2], alo[2][2];
  {
    const float* qrow = Q + ((size_t)(b * LQ + qc * 64)) * DM + h * DH;
#pragma unroll
    for (int qt = 0; qt < 2; ++qt)
#pragma unroll
      for (int c = 0; c < 2; ++c) {
        const float* p = qrow + (size_t)(w * 32 + qt * 16 + l15) * DM + c * 32 + quad * 8;
        float4 x0 = *(const float4*)p;
        float4 x1 = *(const float4*)(p + 4);
        f16x8 hi, lo;
#define QCV(i, xx) { float x_ = (xx); _Float16 hh = (_Float16)x_; hi[i] = hh; lo[i] = (_Float16)(x_ - (float)hh); }
        QCV(0, x0.x) QCV(1, x0.y) QCV(2, x0.z) QCV(3, x0.w)
        QCV(4, x1.x) QCV(5, x1.y) QCV(6, x1.z) QCV(7, x1.w)
#undef QCV
        ahi[qt][c] = hi;
        alo[qt][c] = lo;
      }
  }

  int bsw0 = quad ^ (l15 & 7);
  int bsw1 = (quad + 4) ^ (l15 & 7);
  const float C1 = 0.18033688011112042f;  // SCALE * log2(e)

  double l64[2][4], t64[2][4];
#pragma unroll
  for (int qt = 0; qt < 2; ++qt)
#pragma unroll
    for (int r = 0; r < 4; ++r) { l64[qt][r] = 0.0; t64[qt][r] = 0.0; }

  // Buffer A = kbuf[0..4095], buffer B = kbuf[4096..8191] (f16 units).
  // Within a buffer: hi block 2048 f16 (32 keys x 64), lo block +2048.
  const _Float16* khiA = kbuf;
  const _Float16* kloA = kbuf + 2048;
  const _Float16* khiB = kbuf + 4096;
  const _Float16* kloB = kbuf + 6144;

  // global chunk pair j at +j*16384B. Sub A: hi {0,2048}, lo {8192,10240};
  // sub B: hi {4096,6144}, lo {12288,14336}. 128 thr x 16B = 2KB per issue.
  const char* gp = (const char*)(ksp + ((size_t)(bh * 32 + sp * 16)) * 8192) + t * 16;
  char* ldsA = (char*)kbuf + w * 1024;          // wave-uniform dests
  char* ldsB = (char*)kbuf + 8192 + w * 1024;

#define STAGE_A()                                                               \
  { GL2LDS16(gp, ldsA);            GL2LDS16(gp + 2048, ldsA + 2048);            \
    GL2LDS16(gp + 8192, ldsA + 4096); GL2LDS16(gp + 10240, ldsA + 6144); }
#define STAGE_B()                                                               \
  { GL2LDS16(gp + 4096, ldsB);     GL2LDS16(gp + 6144, ldsB + 2048);            \
    GL2LDS16(gp + 12288, ldsB + 4096); GL2LDS16(gp + 14336, ldsB + 6144); }

  // 2-kt compute of one 32-key sub-chunk into l32/t32; setprio(1) tight
  // around each 6-MFMA dependent chain (T5).
#define KLSTEP(KHI, KLO)                                                        \
  _Pragma("unroll")                                                             \
  for (int kt = 0; kt < 2; ++kt) {                                              \
    int key = kt * 16 + l15;                                                    \
    f16x8 bhi0 = *(const f16x8*)((KHI) + key * 64 + bsw0 * 8);                  \
    f16x8 bhi1 = *(const f16x8*)((KHI) + key * 64 + bsw1 * 8);                  \
    f16x8 blo0 = *(const f16x8*)((KLO) + key * 64 + bsw0 * 8);                  \
    f16x8 blo1 = *(const f16x8*)((KLO) + key * 64 + bsw1 * 8);                  \
    _Pragma("unroll")                                                           \
    for (int qt = 0; qt < 2; ++qt) {                                            \
      f32x4 cacc = {0.f, 0.f, 0.f, 0.f};                                        \
      __builtin_amdgcn_s_setprio(1);                                            \
      cacc = __builtin_amdgcn_mfma_f32_16x16x32_f16(alo[qt][0], bhi0, cacc, 0, 0, 0); \
      cacc = __builtin_amdgcn_mfma_f32_16x16x32_f16(alo[qt][1], bhi1, cacc, 0, 0, 0); \
      cacc = __builtin_amdgcn_mfma_f32_16x16x32_f16(ahi[qt][0], blo0, cacc, 0, 0, 0); \
      cacc = __builtin_amdgcn_mfma_f32_16x16x32_f16(ahi[qt][1], blo1, cacc, 0, 0, 0); \
      cacc = __builtin_amdgcn_mfma_f32_16x16x32_f16(ahi[qt][0], bhi0, cacc, 0, 0, 0); \
      cacc = __builtin_amdgcn_mfma_f32_16x16x32_f16(ahi[qt][1], bhi1, cacc, 0, 0, 0); \
      __builtin_amdgcn_s_setprio(0);                                            \
      _Pragma("unroll")                                                         \
      for (int r = 0; r < 4; ++r) {                                             \
        float rr = cacc[r];                                                     \
        float e = EXP2F(rr * C1);                                               \
        l32[qt][r] += e;                                                        \
        t32[qt][r] = fmaf(rr, e, t32[qt][r]);                                   \
      }                                                                         \
    }                                                                           \
  }

  float l32[2][4], t32[2][4];
#pragma unroll
  for (int qt = 0; qt < 2; ++qt)
#pragma unroll
    for (int r = 0; r < 4; ++r) { l32[qt][r] = 0.f; t32[qt][r] = 0.f; }

  // prologue: stage sub-chunk 0 into A
  STAGE_A();
  __syncthreads();

  for (int j = 0; j < 16; ++j) {
    STAGE_B();                      // overlaps compute of A

    KLSTEP(khiA, kloA)
    __syncthreads();                // B ready (drain hidden under A compute); A free

    if (j < 15) {
      gp += 16384;                  // next pair base
      STAGE_A();                    // overlaps compute of B
    }

    KLSTEP(khiB, kloB)

    if (j & 1) {                    // fold every 128 keys (r9-validated cadence)
#pragma unroll
      for (int qt = 0; qt < 2; ++qt)
#pragma unroll
        for (int r = 0; r < 4; ++r) {
          l64[qt][r] += (double)l32[qt][r];
          t64[qt][r] += (double)t32[qt][r];
          l32[qt][r] = 0.f;
          t32[qt][r] = 0.f;
        }
    }
    __syncthreads();                // A ready for next j; B free
  }
#undef KLSTEP
#undef STAGE_A
#undef STAGE_B

#pragma unroll
  for (int qt = 0; qt < 2; ++qt)
#pragma unroll
    for (int r = 0; r < 4; ++r) {
      double lv = l64[qt][r], tv = t64[qt][r];
#pragma unroll
      for (int m = 1; m < 16; m <<= 1) {
        lv += __shfl_xor(lv, m);
        tv += __shfl_xor(tv, m);
      }
      if (l15 == 0) {
        int qg = qc * 64 + w * 32 + qt * 16 + quad * 4 + r;
        double* dst = lt + ((size_t)(sp * 64 + bh) * LQ + qg) * 2;
        dst[0] = lv;
        dst[1] = tv;
      }
    }
}

// ---------------------------------------------------------------------------
// topk2: single wave per (b,h) -- ZERO barriers. Unchanged.
// ---------------------------------------------------------------------------
__global__ __launch_bounds__(64) void topk2(const double* __restrict__ lt,
                                            int* __restrict__ idxout,
                                            signed char* __restrict__ selmask) {
  int bh = blockIdx.x;
  int lane = threadIdx.x;
  __shared__ double vals[LQ];
  const double logL = 7.624618986159398;
  double bv = -INFINITY;
  int bi = LQ;
  for (int j = 0; j < 32; ++j) {
    int i = j * 64 + lane;
    const double* p0 = lt + ((size_t)bh * LQ + i) * 2;
    const double* p1 = lt + ((size_t)(64 + bh) * LQ + i) * 2;
    double l = p0[0] + p1[0];
    double tt = p0[1] + p1[1];
    double v = 0.125 * (tt / l) - log(l) + logL;
    vals[i] = v;
    selmask[bh * LQ + i] = -1;
    if (v > bv) { bv = v; bi = i; }   // ascending i -> strict > keeps lowest
  }
  for (int u = 0; u < UU; ++u) {
    double gv = bv;
    int gi = bi;
#pragma unroll
    for (int m = 1; m < 64; m <<= 1) {
      double ov = __shfl_xor(gv, m);
      int oi = __shfl_xor(gi, m);
      if (ov > gv || (ov == gv && oi < gi)) { gv = ov; gi = oi; }
    }
    if (lane == 0) {
      idxout[bh * UU + u] = gi;
      selmask[bh * LQ + gi] = (signed char)u;
    }
    if ((gi & 63) == lane) {     // only the owner's local state is stale
      vals[gi] = -INFINITY;
      bv = -INFINITY;
      bi = LQ;
      for (int j = 0; j < 32; ++j) {
        int i = j * 64 + lane;
        double v = vals[i];
        if (v > bv) { bv = v; bi = i; }
      }
    }
  }
}

// ---------------------------------------------------------------------------
// attn_w_mfma: unchanged from r10 (DMA staging, unnormalized wout).
// ---------------------------------------------------------------------------
__global__ __launch_bounds__(256) void attn_w_mfma(const float* __restrict__ Q,
                                                   const _Float16* __restrict__ ksp,
                                                   const int* __restrict__ sel,
                                                   float* __restrict__ wout,
                                                   float* __restrict__ lpart) {
  int bh = blockIdx.x >> 4;
  int ks = blockIdx.x & 15;
  int b = bh >> 4, h = bh & 15;
  int t = threadIdx.x;
  int lane = t & 63, w = t >> 6;
  int quad = lane >> 4, l15 = lane & 15;

  __shared__ __align__(16) _Float16 kbuf[8192];   // 16 KB chunk image
  __shared__ float els[48 * 132];                 // 25.3 KB
  __shared__ int sidx[UU];

  if (t < UU) sidx[t] = sel[bh * UU + t];
  __syncthreads();

  f16x8 ahi[3][2], alo[3][2];
#pragma unroll
  for (int qt = 0; qt < 3; ++qt) {
    int u = qt * 16 + l15;
    if (u > 37) u = 37;                           // duplicate row 37 for pads
    const float* qrow = Q + ((size_t)(b * LQ + sidx[u])) * DM + h * DH;
#pragma unroll
    for (int c = 0; c < 2; ++c) {
      const float* p = qrow + c * 32 + quad * 8;
      float4 x0 = *(const float4*)p;
      float4 x1 = *(const float4*)(p + 4);
      f16x8 hi, lo;
#define QCV(i, xx) { float x_ = (xx); _Float16 hh = (_Float16)x_; hi[i] = hh; lo[i] = (_Float16)(x_ - (float)hh); }
      QCV(0, x0.x) QCV(1, x0.y) QCV(2, x0.z) QCV(3, x0.w)
      QCV(4, x1.x) QCV(5, x1.y) QCV(6, x1.z) QCV(7, x1.w)
#undef QCV
      ahi[qt][c] = hi;
      alo[qt][c] = lo;
    }
  }

  int bsw0 = quad ^ (l15 & 7);
  int bsw1 = (quad + 4) ^ (l15 & 7);
  const float C1 = 0.18033688011112042f;
  const char* gch = (const char*)(ksp + ((size_t)(bh * 32 + ks * 2)) * 8192);
  _Float16* khi = kbuf;
  _Float16* klo = kbuf + 4096;

  for (int chunk = 0; chunk < 2; ++chunk) {
    __syncthreads();
    {
      const char* gs = gch + (size_t)chunk * 16384 + (size_t)t * 16;
      char* ls = (char*)kbuf + (size_t)(w * 64) * 16;
#pragma unroll
      for (int i = 0; i < 4; ++i)
        GL2LDS16(gs + i * 4096, ls + i * 4096);
    }
    __syncthreads();
    int key = w * 16 + l15;
    f16x8 bhi0 = *(const f16x8*)(khi + key * 64 + bsw0 * 8);
    f16x8 bhi1 = *(const f16x8*)(khi + key * 64 + bsw1 * 8);
    f16x8 blo0 = *(const f16x8*)(klo + key * 64 + bsw0 * 8);
    f16x8 blo1 = *(const f16x8*)(klo + key * 64 + bsw1 * 8);
#pragma unroll
    for (int qt = 0; qt < 3; ++qt) {
      f32x4 cacc = {0.f, 0.f, 0.f, 0.f};
      cacc = __builtin_amdgcn_mfma_f32_16x16x32_f16(alo[qt][0], bhi0, cacc, 0, 0, 0);
      cacc = __builtin_amdgcn_mfma_f32_16x16x32_f16(alo[qt][1], bhi1, cacc, 0, 0, 0);
      cacc = __builtin_amdgcn_mfma_f32_16x16x32_f16(ahi[qt][0], blo0, cacc, 0, 0, 0);
      cacc = __builtin_amdgcn_mfma_f32_16x16x32_f16(ahi[qt][1], blo1, cacc, 0, 0, 0);
      cacc = __builtin_amdgcn_mfma_f32_16x16x32_f16(ahi[qt][0], bhi0, cacc, 0, 0, 0);
      cacc = __builtin_amdgcn_mfma_f32_16x16x32_f16(ahi[qt][1], bhi1, cacc, 0, 0, 0);
#pragma unroll
      for (int r = 0; r < 4; ++r) {
        float e = EXP2F(cacc[r] * C1);
        els[(qt * 16 + quad * 4 + r) * 132 + chunk * 64 + w * 16 + l15] = e;
      }
    }
  }
  __syncthreads();

  // coalesced dump (rows 38-47 never touched)
  for (int i = t; i < UU * 128; i += 256) {
    int u = i >> 7, k = i & 127;
    wout[((size_t)(bh * UU + u)) * LQ + ks * 128 + k] = els[u * 132 + k];
  }

  // row sums -> lpart: wave w reduces rows u = w + 4p
#pragma unroll
  for (int p = 0; p < 10; ++p) {
    int u = w + 4 * p;
    if (u < UU) {
      float s = els[u * 132 + lane] + els[u * 132 + 64 + lane];
#pragma unroll
      for (int m = 1; m < 64; m <<= 1) s += __shfl_xor(s, m);
      if (lane == 0) lpart[(bh * 16 + ks) * UU + u] = s;
    }
  }
}

// ---------------------------------------------------------------------------
// attn_pv2: unchanged from r9 (normalization fused here; opart pre-normalized).
// ---------------------------------------------------------------------------
__global__ __launch_bounds__(256) void attn_pv2(const float* __restrict__ V,
                                                float* __restrict__ wout,
                                                const float* __restrict__ lpart,
                                                float* __restrict__ opart) {
  int bh = blockIdx.x >> 4;
  int ks = blockIdx.x & 15;
  int b = bh >> 4, h = bh & 15;
  int t = threadIdx.x;
  int d = t & 63, ug = t >> 6;

  __shared__ float ps[40 * 132];   // rows 38,39 zeroed (pad accumulators)
  __shared__ float l3s[UU];        // 1 / full row sum

  if (t < UU) {
    float s = 0.f;
#pragma unroll
    for (int i = 0; i < 16; ++i) s += lpart[(bh * 16 + i) * UU + t];
    l3s[t] = 1.f / s;
  }
  for (int i = t; i < 2 * 132; i += 256) ps[UU * 132 + i] = 0.f;
  __syncthreads();

  for (int i = t; i < UU * 32; i += 256) {
    int u = i >> 5, d4 = i & 31;
    float r = l3s[u];
    float* wp = wout + ((size_t)(bh * UU + u)) * LQ + ks * 128 + d4 * 4;
    float4 v = *(const float4*)wp;
    v.x *= r; v.y *= r; v.z *= r; v.w *= r;
    *(float4*)(ps + u * 132 + d4 * 4) = v;
    *(float4*)wp = v;                 // wout now final (normalized weights)
  }
  __syncthreads();

  const float* vbase = V + ((size_t)(b * LQ + ks * 128)) * DM + h * DH + d;
  float o[10];
#pragma unroll
  for (int p = 0; p < 10; ++p) o[p] = 0.f;

  for (int j4 = 0; j4 < 128; j4 += 4) {
    float v0 = vbase[(size_t)(j4 + 0) * DM];
    float v1 = vbase[(size_t)(j4 + 1) * DM];
    float v2 = vbase[(size_t)(j4 + 2) * DM];
    float v3 = vbase[(size_t)(j4 + 3) * DM];
#pragma unroll
    for (int p = 0; p < 10; ++p) {
      float4 pw = *(const float4*)(ps + (ug + 4 * p) * 132 + j4);
      o[p] = fmaf(pw.x, v0, o[p]);
      o[p] = fmaf(pw.y, v1, o[p]);
      o[p] = fmaf(pw.z, v2, o[p]);
      o[p] = fmaf(pw.w, v3, o[p]);
    }
  }

#pragma unroll
  for (int p = 0; p < 10; ++p) {
    int u = ug + 4 * p;
    if (u < UU) opart[((size_t)((bh * 16 + ks) * UU + u)) * DH + d] = o[p];
  }
}

// ---------------------------------------------------------------------------
// writeout: unchanged from r9 -- dense-output pass only.
// ---------------------------------------------------------------------------
__global__ __launch_bounds__(256) void writeout_kernel(const signed char* __restrict__ selmask,
                                                       const float* __restrict__ opart,
                                                       float* __restrict__ out) {
  int i2 = blockIdx.x * 256 + threadIdx.x;   // < 8,388,608 (exact grid)
  int d = i2 & 63;
  int h = (i2 >> 6) & 15;
  int q = (i2 >> 10) & 2047;
  int b = i2 >> 21;
  int bh = b * 16 + h;
  int u = selmask[bh * LQ + q];
  float val = 0.f;
  if (u >= 0) {
    float s = 0.f;
#pragma unroll
    for (int p = 0; p < 16; ++p)
      s += opart[((size_t)((bh * 16 + p) * UU + u)) * DH + d];
    val = s;
  }
  out[i2] = val;
}

extern "C" void kernel_launch(void* const* d_in, const int* in_sizes, int n_in,
                              void* d_out, int out_size, void* d_ws, size_t ws_size,
                              hipStream_t stream) {
  (void)in_sizes; (void)n_in;
  if (ws_size < F_NEED) return;   // fail visibly (poisoned out) over UB; r8 confirmed fit
  const float* Q = (const float*)d_in[0];
  const float* K = (const float*)d_in[1];
  const float* V = (const float*)d_in[2];
  float* out = (float*)d_out;
  float* wout = out + (size_t)4 * LQ * DM;
  char* ws = (char*)d_ws;

  double* lt = (double*)ws;
  int* sel = (int*)(ws + F_OFF_SEL);
  signed char* mask = (signed char*)(ws + F_OFF_MASK);
  float* lpart = (float*)(ws + F_OFF_LPART);
  _Float16* ksp = (_Float16*)(ws + F_OFF_KSP);
  float* opart = (float*)(ws + F_OFF_KSP);   // aliases ksp, stream-ordered safe

  ksplit_kernel<<<4096, 256, 0, stream>>>(K, ksp);
  kl_mfma2<<<4096, 128, 0, stream>>>(Q, ksp, lt);
  topk2<<<NBH, 64, 0, stream>>>(lt, sel, mask);
  attn_w_mfma<<<NBH * 16, 256, 0, stream>>>(Q, ksp, sel, wout, lpart);
  attn_pv2<<<NBH * 16, 256, 0, stream>>>(V, wout, lpart, opart);
  writeout_kernel<<<(4 * LQ * DM) / 256, 256, 0, stream>>>(mask, opart, out);
}

// Round 4
// 350.827 us; speedup vs baseline: 1.0428x; 1.0428x over previous
//
#include <hip/hip_runtime.h>
#include <math.h>

#define LQ 2048
#define DM 1024
#define NH 16
#define DH 64
#define UU 38
#define NBH 64            // B*NH = 4*16
#define SCALE 0.125f      // 1/sqrt(64)

typedef _Float16 f16x8 __attribute__((ext_vector_type(8)));
typedef float f32x4 __attribute__((ext_vector_type(4)));
typedef float f32x2 __attribute__((ext_vector_type(2)));

#if __has_builtin(__builtin_amdgcn_exp2f)
#define EXP2F(x) __builtin_amdgcn_exp2f(x)
#else
#define EXP2F(x) exp2f(x)
#endif

// async global->LDS DMA, 16B per lane. LDS dest is wave-uniform base + lane*16.
#define GL2LDS16(gp, lp)                                           \
  __builtin_amdgcn_global_load_lds(                                \
      (const __attribute__((address_space(1))) void*)(gp),         \
      (__attribute__((address_space(3))) void*)(lp), 16, 0, 0)

// ---- workspace layout (bytes), total 40,700,928 (proven to fit in r8) ----
//   lt    : [2][64][2048][2] f64           [0, 4194304)
//   sel   : 64*38 int                       +9728
//   l3    : 64*38 f32 (UNUSED since r9 -- slot kept for layout stability)
//   mask  : [64][2048] s8                   +131072
//   lpart : [64][16][38] f32                +155648 (region 311296)
//   ksp   : [64][32][8192] f16 @ 7146496    (33,554,432 B)
//   opart : [64][16][38][64] f32 ALIASES ksp (9.96 MB; written by attn_pv2
//           strictly after attn_w_mfma's last ksp read -- stream ordered)
#define F_OFF_SEL   4194304
#define F_OFF_L3    4204032
#define F_OFF_MASK  4213760
#define F_OFF_LPART 4344832
#define F_OFF_KSP   7146496
#define F_NEED      40700928ull

// ---------------------------------------------------------------------------
// ksplit: one-time K fp32 -> fp16 hi/lo split with the conflict-free LDS
// image pre-baked (dim-block p stored at p^(k&7)). Read by kl_mfma2 AND
// attn_w_mfma (second read is L2/L3-hot).
// ---------------------------------------------------------------------------
__global__ __launch_bounds__(256) void ksplit_kernel(const float* __restrict__ K,
                                                     _Float16* __restrict__ ksp) {
  int idx = blockIdx.x * 256 + threadIdx.x;   // 1,048,576 total
  int p = idx & 7;
  int k = (idx >> 3) & 63;
  int kc = (idx >> 9) & 31;
  int bh = idx >> 14;
  int b = bh >> 4, h = bh & 15;
  const float* src = K + ((size_t)(b * LQ + kc * 64 + k)) * DM + h * DH + (p ^ (k & 7)) * 8;
  float4 x0 = *(const float4*)src;
  float4 x1 = *(const float4*)(src + 4);
  f16x8 hi, lo;
#define KCV(i, xx) { float x_ = (xx); _Float16 hh = (_Float16)x_; hi[i] = hh; lo[i] = (_Float16)(x_ - (float)hh); }
  KCV(0, x0.x) KCV(1, x0.y) KCV(2, x0.z) KCV(3, x0.w)
  KCV(4, x1.x) KCV(5, x1.y) KCV(6, x1.z) KCV(7, x1.w)
#undef KCV
  _Float16* base = ksp + ((size_t)(bh * 32 + kc)) * 8192;
  *(f16x8*)(base + k * 64 + p * 8) = hi;
  *(f16x8*)(base + 4096 + k * 64 + p * 8) = lo;
}

// ---------------------------------------------------------------------------
// kl_mfma2 r12: r10 structure EXACTLY (256 thr / 4 waves, 2x8KB dbuf, grid
// 2048 -- measured 128us, passed) with ONE change: the per-score accumulate
// chain runs on f32x2 pairs so the compiler emits packed VOP3P
// (v_pk_mul/add/fma_f32, full-rate). Per-CU VALU busy model: 320 ->
// 224 cyc per wave-j (exp stays scalar trans) => 68 -> 47us busy, below the
// MFMA floor. Summation order per accumulator element unchanged.
// ---------------------------------------------------------------------------
__global__ __launch_bounds__(256) void kl_mfma2(const float* __restrict__ Q,
                                                const _Float16* __restrict__ ksp,
                                                double* __restrict__ lt) {
  int bh = blockIdx.x & 63;
  int qc = (blockIdx.x >> 6) & 15;
  int sp = blockIdx.x >> 10;
  int b = bh >> 4, h = bh & 15;
  int t = threadIdx.x;
  int lane = t & 63, w = t >> 6;
  int quad = lane >> 4, l15 = lane & 15;

  __shared__ __align__(16) _Float16 kbuf[8192];   // 16 KB = 2 x 8 KB dbuf

  f16x8 ahi[2][2], alo[2][2];
  {
    const float* qrow = Q + ((size_t)(b * LQ + qc * 128)) * DM + h * DH;
#pragma unroll
    for (int qt = 0; qt < 2; ++qt)
#pragma unroll
      for (int c = 0; c < 2; ++c) {
        const float* p = qrow + (size_t)(w * 32 + qt * 16 + l15) * DM + c * 32 + quad * 8;
        float4 x0 = *(const float4*)p;
        float4 x1 = *(const float4*)(p + 4);
        f16x8 hi, lo;
#define QCV(i, xx) { float x_ = (xx); _Float16 hh = (_Float16)x_; hi[i] = hh; lo[i] = (_Float16)(x_ - (float)hh); }
        QCV(0, x0.x) QCV(1, x0.y) QCV(2, x0.z) QCV(3, x0.w)
        QCV(4, x1.x) QCV(5, x1.y) QCV(6, x1.z) QCV(7, x1.w)
#undef QCV
        ahi[qt][c] = hi;
        alo[qt][c] = lo;
      }
  }

  int bsw0 = quad ^ (l15 & 7);
  int bsw1 = (quad + 4) ^ (l15 & 7);
  const float C1 = 0.18033688011112042f;  // SCALE * log2(e)

  double l64[2][4], t64[2][4];
#pragma unroll
  for (int qt = 0; qt < 2; ++qt)
#pragma unroll
    for (int r = 0; r < 4; ++r) { l64[qt][r] = 0.0; t64[qt][r] = 0.0; }

  // Buffer A = kbuf[0..4095], buffer B = kbuf[4096..8191] (f16 units).
  // Within a buffer: hi block 2048 f16 (32 keys x 64), lo block +2048.
  const _Float16* khiA = kbuf;
  const _Float16* kloA = kbuf + 2048;
  const _Float16* khiB = kbuf + 4096;
  const _Float16* kloB = kbuf + 6144;

  // global: pair j base = gch + j*16384B; sub-chunk 2j hi at +0, lo at +8192;
  // sub-chunk 2j+1 hi at +4096, lo at +12288.
  const char* gp = (const char*)(ksp + ((size_t)(bh * 32 + sp * 16)) * 8192) + t * 16;
  char* ldsA = (char*)kbuf + w * 1024;          // wave-uniform dests
  char* ldsB = (char*)kbuf + 8192 + w * 1024;

  // 2-kt compute of one 32-key sub-chunk into l32/t32 (packed f32x2 pairs)
#define KLSTEP(KHI, KLO)                                                        \
  _Pragma("unroll")                                                             \
  for (int kt = 0; kt < 2; ++kt) {                                              \
    int key = kt * 16 + l15;                                                    \
    f16x8 bhi0 = *(const f16x8*)((KHI) + key * 64 + bsw0 * 8);                  \
    f16x8 bhi1 = *(const f16x8*)((KHI) + key * 64 + bsw1 * 8);                  \
    f16x8 blo0 = *(const f16x8*)((KLO) + key * 64 + bsw0 * 8);                  \
    f16x8 blo1 = *(const f16x8*)((KLO) + key * 64 + bsw1 * 8);                  \
    _Pragma("unroll")                                                           \
    for (int qt = 0; qt < 2; ++qt) {                                            \
      f32x4 cacc = {0.f, 0.f, 0.f, 0.f};                                        \
      cacc = __builtin_amdgcn_mfma_f32_16x16x32_f16(alo[qt][0], bhi0, cacc, 0, 0, 0); \
      cacc = __builtin_amdgcn_mfma_f32_16x16x32_f16(alo[qt][1], bhi1, cacc, 0, 0, 0); \
      cacc = __builtin_amdgcn_mfma_f32_16x16x32_f16(ahi[qt][0], blo0, cacc, 0, 0, 0); \
      cacc = __builtin_amdgcn_mfma_f32_16x16x32_f16(ahi[qt][1], blo1, cacc, 0, 0, 0); \
      cacc = __builtin_amdgcn_mfma_f32_16x16x32_f16(ahi[qt][0], bhi0, cacc, 0, 0, 0); \
      cacc = __builtin_amdgcn_mfma_f32_16x16x32_f16(ahi[qt][1], bhi1, cacc, 0, 0, 0); \
      _Pragma("unroll")                                                         \
      for (int rp = 0; rp < 2; ++rp) {                                          \
        f32x2 rr = { cacc[2 * rp], cacc[2 * rp + 1] };                          \
        f32x2 sc = rr * C1;                    /* v_pk_mul_f32 */               \
        f32x2 e  = { EXP2F(sc[0]), EXP2F(sc[1]) };                              \
        l32[qt][rp] += e;                      /* v_pk_add_f32 */               \
        t32[qt][rp] += rr * e;                 /* v_pk_fma_f32 */               \
      }                                                                         \
    }                                                                           \
  }

  // prologue: stage sub-chunk 0 into A
  GL2LDS16(gp, ldsA);
  GL2LDS16(gp + 8192, ldsA + 4096);
  __syncthreads();

  for (int j = 0; j < 16; ++j) {
    // stage sub-chunk 2j+1 into B (overlaps compute of A)
    GL2LDS16(gp + 4096, ldsB);
    GL2LDS16(gp + 12288, ldsB + 4096);

    f32x2 l32[2][2], t32[2][2];
#pragma unroll
    for (int qt = 0; qt < 2; ++qt)
#pragma unroll
      for (int rp = 0; rp < 2; ++rp) {
        l32[qt][rp] = (f32x2){0.f, 0.f};
        t32[qt][rp] = (f32x2){0.f, 0.f};
      }

    KLSTEP(khiA, kloA)
    __syncthreads();              // B ready (drain hidden under A compute); A free

    if (j < 15) {
      gp += 16384;                // next pair base
      GL2LDS16(gp, ldsA);         // stage sub-chunk 2j+2 into A (overlaps B compute)
      GL2LDS16(gp + 8192, ldsA + 4096);
    }

    KLSTEP(khiB, kloB)

    // fold every 64 keys (identical cadence/numerics to r10)
#pragma unroll
    for (int qt = 0; qt < 2; ++qt)
#pragma unroll
      for (int rp = 0; rp < 2; ++rp)
#pragma unroll
        for (int c = 0; c < 2; ++c) {
          l64[qt][rp * 2 + c] += (double)l32[qt][rp][c];
          t64[qt][rp * 2 + c] += (double)t32[qt][rp][c];
        }
    __syncthreads();              // A ready for next j; B free
  }
#undef KLSTEP

#pragma unroll
  for (int qt = 0; qt < 2; ++qt)
#pragma unroll
    for (int r = 0; r < 4; ++r) {
      double lv = l64[qt][r], tv = t64[qt][r];
#pragma unroll
      for (int m = 1; m < 16; m <<= 1) {
        lv += __shfl_xor(lv, m);
        tv += __shfl_xor(tv, m);
      }
      if (l15 == 0) {
        int qg = qc * 128 + w * 32 + qt * 16 + quad * 4 + r;
        double* dst = lt + ((size_t)(sp * 64 + bh) * LQ + qg) * 2;
        dst[0] = lv;
        dst[1] = tv;
      }
    }
}

// ---------------------------------------------------------------------------
// topk2: single wave per (b,h) -- ZERO barriers. Unchanged.
// ---------------------------------------------------------------------------
__global__ __launch_bounds__(64) void topk2(const double* __restrict__ lt,
                                            int* __restrict__ idxout,
                                            signed char* __restrict__ selmask) {
  int bh = blockIdx.x;
  int lane = threadIdx.x;
  __shared__ double vals[LQ];
  const double logL = 7.624618986159398;
  double bv = -INFINITY;
  int bi = LQ;
  for (int j = 0; j < 32; ++j) {
    int i = j * 64 + lane;
    const double* p0 = lt + ((size_t)bh * LQ + i) * 2;
    const double* p1 = lt + ((size_t)(64 + bh) * LQ + i) * 2;
    double l = p0[0] + p1[0];
    double tt = p0[1] + p1[1];
    double v = 0.125 * (tt / l) - log(l) + logL;
    vals[i] = v;
    selmask[bh * LQ + i] = -1;
    if (v > bv) { bv = v; bi = i; }   // ascending i -> strict > keeps lowest
  }
  for (int u = 0; u < UU; ++u) {
    double gv = bv;
    int gi = bi;
#pragma unroll
    for (int m = 1; m < 64; m <<= 1) {
      double ov = __shfl_xor(gv, m);
      int oi = __shfl_xor(gi, m);
      if (ov > gv || (ov == gv && oi < gi)) { gv = ov; gi = oi; }
    }
    if (lane == 0) {
      idxout[bh * UU + u] = gi;
      selmask[bh * LQ + gi] = (signed char)u;
    }
    if ((gi & 63) == lane) {     // only the owner's local state is stale
      vals[gi] = -INFINITY;
      bv = -INFINITY;
      bi = LQ;
      for (int j = 0; j < 32; ++j) {
        int i = j * 64 + lane;
        double v = vals[i];
        if (v > bv) { bv = v; bi = i; }
      }
    }
  }
}

// ---------------------------------------------------------------------------
// attn_w_mfma: unchanged from r10 (DMA staging, unnormalized wout).
// ---------------------------------------------------------------------------
__global__ __launch_bounds__(256) void attn_w_mfma(const float* __restrict__ Q,
                                                   const _Float16* __restrict__ ksp,
                                                   const int* __restrict__ sel,
                                                   float* __restrict__ wout,
                                                   float* __restrict__ lpart) {
  int bh = blockIdx.x >> 4;
  int ks = blockIdx.x & 15;
  int b = bh >> 4, h = bh & 15;
  int t = threadIdx.x;
  int lane = t & 63, w = t >> 6;
  int quad = lane >> 4, l15 = lane & 15;

  __shared__ __align__(16) _Float16 kbuf[8192];   // 16 KB chunk image
  __shared__ float els[48 * 132];                 // 25.3 KB
  __shared__ int sidx[UU];

  if (t < UU) sidx[t] = sel[bh * UU + t];
  __syncthreads();

  f16x8 ahi[3][2], alo[3][2];
#pragma unroll
  for (int qt = 0; qt < 3; ++qt) {
    int u = qt * 16 + l15;
    if (u > 37) u = 37;                           // duplicate row 37 for pads
    const float* qrow = Q + ((size_t)(b * LQ + sidx[u])) * DM + h * DH;
#pragma unroll
    for (int c = 0; c < 2; ++c) {
      const float* p = qrow + c * 32 + quad * 8;
      float4 x0 = *(const float4*)p;
      float4 x1 = *(const float4*)(p + 4);
      f16x8 hi, lo;
#define QCV(i, xx) { float x_ = (xx); _Float16 hh = (_Float16)x_; hi[i] = hh; lo[i] = (_Float16)(x_ - (float)hh); }
      QCV(0, x0.x) QCV(1, x0.y) QCV(2, x0.z) QCV(3, x0.w)
      QCV(4, x1.x) QCV(5, x1.y) QCV(6, x1.z) QCV(7, x1.w)
#undef QCV
      ahi[qt][c] = hi;
      alo[qt][c] = lo;
    }
  }

  int bsw0 = quad ^ (l15 & 7);
  int bsw1 = (quad + 4) ^ (l15 & 7);
  const float C1 = 0.18033688011112042f;
  const char* gch = (const char*)(ksp + ((size_t)(bh * 32 + ks * 2)) * 8192);
  _Float16* khi = kbuf;
  _Float16* klo = kbuf + 4096;

  for (int chunk = 0; chunk < 2; ++chunk) {
    __syncthreads();
    {
      const char* gs = gch + (size_t)chunk * 16384 + (size_t)t * 16;
      char* ls = (char*)kbuf + (size_t)(w * 64) * 16;
#pragma unroll
      for (int i = 0; i < 4; ++i)
        GL2LDS16(gs + i * 4096, ls + i * 4096);
    }
    __syncthreads();
    int key = w * 16 + l15;
    f16x8 bhi0 = *(const f16x8*)(khi + key * 64 + bsw0 * 8);
    f16x8 bhi1 = *(const f16x8*)(khi + key * 64 + bsw1 * 8);
    f16x8 blo0 = *(const f16x8*)(klo + key * 64 + bsw0 * 8);
    f16x8 blo1 = *(const f16x8*)(klo + key * 64 + bsw1 * 8);
#pragma unroll
    for (int qt = 0; qt < 3; ++qt) {
      f32x4 cacc = {0.f, 0.f, 0.f, 0.f};
      cacc = __builtin_amdgcn_mfma_f32_16x16x32_f16(alo[qt][0], bhi0, cacc, 0, 0, 0);
      cacc = __builtin_amdgcn_mfma_f32_16x16x32_f16(alo[qt][1], bhi1, cacc, 0, 0, 0);
      cacc = __builtin_amdgcn_mfma_f32_16x16x32_f16(ahi[qt][0], blo0, cacc, 0, 0, 0);
      cacc = __builtin_amdgcn_mfma_f32_16x16x32_f16(ahi[qt][1], blo1, cacc, 0, 0, 0);
      cacc = __builtin_amdgcn_mfma_f32_16x16x32_f16(ahi[qt][0], bhi0, cacc, 0, 0, 0);
      cacc = __builtin_amdgcn_mfma_f32_16x16x32_f16(ahi[qt][1], bhi1, cacc, 0, 0, 0);
#pragma unroll
      for (int r = 0; r < 4; ++r) {
        float e = EXP2F(cacc[r] * C1);
        els[(qt * 16 + quad * 4 + r) * 132 + chunk * 64 + w * 16 + l15] = e;
      }
    }
  }
  __syncthreads();

  // coalesced dump (rows 38-47 never touched)
  for (int i = t; i < UU * 128; i += 256) {
    int u = i >> 7, k = i & 127;
    wout[((size_t)(bh * UU + u)) * LQ + ks * 128 + k] = els[u * 132 + k];
  }

  // row sums -> lpart: wave w reduces rows u = w + 4p
#pragma unroll
  for (int p = 0; p < 10; ++p) {
    int u = w + 4 * p;
    if (u < UU) {
      float s = els[u * 132 + lane] + els[u * 132 + 64 + lane];
#pragma unroll
      for (int m = 1; m < 64; m <<= 1) s += __shfl_xor(s, m);
      if (lane == 0) lpart[(bh * 16 + ks) * UU + u] = s;
    }
  }
}

// ---------------------------------------------------------------------------
// attn_pv2: unchanged from r9 (normalization fused here; opart pre-normalized).
// ---------------------------------------------------------------------------
__global__ __launch_bounds__(256) void attn_pv2(const float* __restrict__ V,
                                                float* __restrict__ wout,
                                                const float* __restrict__ lpart,
                                                float* __restrict__ opart) {
  int bh = blockIdx.x >> 4;
  int ks = blockIdx.x & 15;
  int b = bh >> 4, h = bh & 15;
  int t = threadIdx.x;
  int d = t & 63, ug = t >> 6;

  __shared__ float ps[40 * 132];   // rows 38,39 zeroed (pad accumulators)
  __shared__ float l3s[UU];        // 1 / full row sum

  if (t < UU) {
    float s = 0.f;
#pragma unroll
    for (int i = 0; i < 16; ++i) s += lpart[(bh * 16 + i) * UU + t];
    l3s[t] = 1.f / s;
  }
  for (int i = t; i < 2 * 132; i += 256) ps[UU * 132 + i] = 0.f;
  __syncthreads();

  for (int i = t; i < UU * 32; i += 256) {
    int u = i >> 5, d4 = i & 31;
    float r = l3s[u];
    float* wp = wout + ((size_t)(bh * UU + u)) * LQ + ks * 128 + d4 * 4;
    float4 v = *(const float4*)wp;
    v.x *= r; v.y *= r; v.z *= r; v.w *= r;
    *(float4*)(ps + u * 132 + d4 * 4) = v;
    *(float4*)wp = v;                 // wout now final (normalized weights)
  }
  __syncthreads();

  const float* vbase = V + ((size_t)(b * LQ + ks * 128)) * DM + h * DH + d;
  float o[10];
#pragma unroll
  for (int p = 0; p < 10; ++p) o[p] = 0.f;

  for (int j4 = 0; j4 < 128; j4 += 4) {
    float v0 = vbase[(size_t)(j4 + 0) * DM];
    float v1 = vbase[(size_t)(j4 + 1) * DM];
    float v2 = vbase[(size_t)(j4 + 2) * DM];
    float v3 = vbase[(size_t)(j4 + 3) * DM];
#pragma unroll
    for (int p = 0; p < 10; ++p) {
      float4 pw = *(const float4*)(ps + (ug + 4 * p) * 132 + j4);
      o[p] = fmaf(pw.x, v0, o[p]);
      o[p] = fmaf(pw.y, v1, o[p]);
      o[p] = fmaf(pw.z, v2, o[p]);
      o[p] = fmaf(pw.w, v3, o[p]);
    }
  }

#pragma unroll
  for (int p = 0; p < 10; ++p) {
    int u = ug + 4 * p;
    if (u < UU) opart[((size_t)((bh * 16 + ks) * UU + u)) * DH + d] = o[p];
  }
}

// ---------------------------------------------------------------------------
// writeout: unchanged from r9 -- dense-output pass only.
// ---------------------------------------------------------------------------
__global__ __launch_bounds__(256) void writeout_kernel(const signed char* __restrict__ selmask,
                                                       const float* __restrict__ opart,
                                                       float* __restrict__ out) {
  int i2 = blockIdx.x * 256 + threadIdx.x;   // < 8,388,608 (exact grid)
  int d = i2 & 63;
  int h = (i2 >> 6) & 15;
  int q = (i2 >> 10) & 2047;
  int b = i2 >> 21;
  int bh = b * 16 + h;
  int u = selmask[bh * LQ + q];
  float val = 0.f;
  if (u >= 0) {
    float s = 0.f;
#pragma unroll
    for (int p = 0; p < 16; ++p)
      s += opart[((size_t)((bh * 16 + p) * UU + u)) * DH + d];
    val = s;
  }
  out[i2] = val;
}

extern "C" void kernel_launch(void* const* d_in, const int* in_sizes, int n_in,
                              void* d_out, int out_size, void* d_ws, size_t ws_size,
                              hipStream_t stream) {
  (void)in_sizes; (void)n_in;
  if (ws_size < F_NEED) return;   // fail visibly (poisoned out) over UB; r8 confirmed fit
  const float* Q = (const float*)d_in[0];
  const float* K = (const float*)d_in[1];
  const float* V = (const float*)d_in[2];
  float* out = (float*)d_out;
  float* wout = out + (size_t)4 * LQ * DM;
  char* ws = (char*)d_ws;

  double* lt = (double*)ws;
  int* sel = (int*)(ws + F_OFF_SEL);
  signed char* mask = (signed char*)(ws + F_OFF_MASK);
  float* lpart = (float*)(ws + F_OFF_LPART);
  _Float16* ksp = (_Float16*)(ws + F_OFF_KSP);
  float* opart = (float*)(ws + F_OFF_KSP);   // aliases ksp, stream-ordered safe

  ksplit_kernel<<<4096, 256, 0, stream>>>(K, ksp);
  kl_mfma2<<<2048, 256, 0, stream>>>(Q, ksp, lt);
  topk2<<<NBH, 64, 0, stream>>>(lt, sel, mask);
  attn_w_mfma<<<NBH * 16, 256, 0, stream>>>(Q, ksp, sel, wout, lpart);
  attn_pv2<<<NBH * 16, 256, 0, stream>>>(V, wout, lpart, opart);
  writeout_kernel<<<(4 * LQ * DM) / 256, 256, 0, stream>>>(mask, opart, out);
}

// Round 5
// 344.213 us; speedup vs baseline: 1.0629x; 1.0192x over previous
//
#include <hip/hip_runtime.h>
#include <math.h>

#define LQ 2048
#define DM 1024
#define NH 16
#define DH 64
#define UU 38
#define NBH 64            // B*NH = 4*16
#define SCALE 0.125f      // 1/sqrt(64)

typedef _Float16 f16x8 __attribute__((ext_vector_type(8)));
typedef float f32x4 __attribute__((ext_vector_type(4)));
typedef float f32x2 __attribute__((ext_vector_type(2)));

#if __has_builtin(__builtin_amdgcn_exp2f)
#define EXP2F(x) __builtin_amdgcn_exp2f(x)
#else
#define EXP2F(x) exp2f(x)
#endif

// async global->LDS DMA, 16B per lane. LDS dest is wave-uniform base + lane*16.
#define GL2LDS16(gp, lp)                                           \
  __builtin_amdgcn_global_load_lds(                                \
      (const __attribute__((address_space(1))) void*)(gp),         \
      (__attribute__((address_space(3))) void*)(lp), 16, 0, 0)

// ---- workspace layout (bytes), total 40,700,928 (proven to fit in r8) ----
//   lt    : [2][64][2048][2] f64           [0, 4194304)
//   sel   : 64*38 int                       +9728
//   l3    : 64*38 f32 (UNUSED since r9 -- slot kept for layout stability)
//   mask  : [64][2048] s8                   +131072
//   lpart : [64][16][38] f32                +155648 (region 311296)
//   ksp   : [64][32][8192] f16 @ 7146496    (33,554,432 B)
//   opart : [64][16][38][64] f32 ALIASES ksp (9.96 MB; written by attn_pv2
//           strictly after attn_w_mfma's last ksp read -- stream ordered)
#define F_OFF_SEL   4194304
#define F_OFF_L3    4204032
#define F_OFF_MASK  4213760
#define F_OFF_LPART 4344832
#define F_OFF_KSP   7146496
#define F_NEED      40700928ull

// ---------------------------------------------------------------------------
// ksplit: one-time K fp32 -> fp16 hi/lo split with the conflict-free LDS
// image pre-baked (dim-block p stored at p^(k&7)). Read by kl_mfma2 AND
// attn_w_mfma (second read is L2/L3-hot).
// ---------------------------------------------------------------------------
__global__ __launch_bounds__(256) void ksplit_kernel(const float* __restrict__ K,
                                                     _Float16* __restrict__ ksp) {
  int idx = blockIdx.x * 256 + threadIdx.x;   // 1,048,576 total
  int p = idx & 7;
  int k = (idx >> 3) & 63;
  int kc = (idx >> 9) & 31;
  int bh = idx >> 14;
  int b = bh >> 4, h = bh & 15;
  const float* src = K + ((size_t)(b * LQ + kc * 64 + k)) * DM + h * DH + (p ^ (k & 7)) * 8;
  float4 x0 = *(const float4*)src;
  float4 x1 = *(const float4*)(src + 4);
  f16x8 hi, lo;
#define KCV(i, xx) { float x_ = (xx); _Float16 hh = (_Float16)x_; hi[i] = hh; lo[i] = (_Float16)(x_ - (float)hh); }
  KCV(0, x0.x) KCV(1, x0.y) KCV(2, x0.z) KCV(3, x0.w)
  KCV(4, x1.x) KCV(5, x1.y) KCV(6, x1.z) KCV(7, x1.w)
#undef KCV
  _Float16* base = ksp + ((size_t)(bh * 32 + kc)) * 8192;
  *(f16x8*)(base + k * 64 + p * 8) = hi;
  *(f16x8*)(base + 4096 + k * 64 + p * 8) = lo;
}

// ---------------------------------------------------------------------------
// kl_mfma2: r12 state (validated 128us). 256 thr, 2x8KB dbuf DMA staging,
// packed f32x2 accumulate chain, f64 fold every 64 keys. At its structural
// floor (MFMA 45us + VALU 58us + LDS 41us busy, partial overlap).
// ---------------------------------------------------------------------------
__global__ __launch_bounds__(256) void kl_mfma2(const float* __restrict__ Q,
                                                const _Float16* __restrict__ ksp,
                                                double* __restrict__ lt) {
  int bh = blockIdx.x & 63;
  int qc = (blockIdx.x >> 6) & 15;
  int sp = blockIdx.x >> 10;
  int b = bh >> 4, h = bh & 15;
  int t = threadIdx.x;
  int lane = t & 63, w = t >> 6;
  int quad = lane >> 4, l15 = lane & 15;

  __shared__ __align__(16) _Float16 kbuf[8192];   // 16 KB = 2 x 8 KB dbuf

  f16x8 ahi[2][2], alo[2][2];
  {
    const float* qrow = Q + ((size_t)(b * LQ + qc * 128)) * DM + h * DH;
#pragma unroll
    for (int qt = 0; qt < 2; ++qt)
#pragma unroll
      for (int c = 0; c < 2; ++c) {
        const float* p = qrow + (size_t)(w * 32 + qt * 16 + l15) * DM + c * 32 + quad * 8;
        float4 x0 = *(const float4*)p;
        float4 x1 = *(const float4*)(p + 4);
        f16x8 hi, lo;
#define QCV(i, xx) { float x_ = (xx); _Float16 hh = (_Float16)x_; hi[i] = hh; lo[i] = (_Float16)(x_ - (float)hh); }
        QCV(0, x0.x) QCV(1, x0.y) QCV(2, x0.z) QCV(3, x0.w)
        QCV(4, x1.x) QCV(5, x1.y) QCV(6, x1.z) QCV(7, x1.w)
#undef QCV
        ahi[qt][c] = hi;
        alo[qt][c] = lo;
      }
  }

  int bsw0 = quad ^ (l15 & 7);
  int bsw1 = (quad + 4) ^ (l15 & 7);
  const float C1 = 0.18033688011112042f;  // SCALE * log2(e)

  double l64[2][4], t64[2][4];
#pragma unroll
  for (int qt = 0; qt < 2; ++qt)
#pragma unroll
    for (int r = 0; r < 4; ++r) { l64[qt][r] = 0.0; t64[qt][r] = 0.0; }

  // Buffer A = kbuf[0..4095], buffer B = kbuf[4096..8191] (f16 units).
  // Within a buffer: hi block 2048 f16 (32 keys x 64), lo block +2048.
  const _Float16* khiA = kbuf;
  const _Float16* kloA = kbuf + 2048;
  const _Float16* khiB = kbuf + 4096;
  const _Float16* kloB = kbuf + 6144;

  // global: pair j base = gch + j*16384B; sub-chunk 2j hi at +0, lo at +8192;
  // sub-chunk 2j+1 hi at +4096, lo at +12288.
  const char* gp = (const char*)(ksp + ((size_t)(bh * 32 + sp * 16)) * 8192) + t * 16;
  char* ldsA = (char*)kbuf + w * 1024;          // wave-uniform dests
  char* ldsB = (char*)kbuf + 8192 + w * 1024;

  // 2-kt compute of one 32-key sub-chunk into l32/t32 (packed f32x2 pairs)
#define KLSTEP(KHI, KLO)                                                        \
  _Pragma("unroll")                                                             \
  for (int kt = 0; kt < 2; ++kt) {                                              \
    int key = kt * 16 + l15;                                                    \
    f16x8 bhi0 = *(const f16x8*)((KHI) + key * 64 + bsw0 * 8);                  \
    f16x8 bhi1 = *(const f16x8*)((KHI) + key * 64 + bsw1 * 8);                  \
    f16x8 blo0 = *(const f16x8*)((KLO) + key * 64 + bsw0 * 8);                  \
    f16x8 blo1 = *(const f16x8*)((KLO) + key * 64 + bsw1 * 8);                  \
    _Pragma("unroll")                                                           \
    for (int qt = 0; qt < 2; ++qt) {                                            \
      f32x4 cacc = {0.f, 0.f, 0.f, 0.f};                                        \
      cacc = __builtin_amdgcn_mfma_f32_16x16x32_f16(alo[qt][0], bhi0, cacc, 0, 0, 0); \
      cacc = __builtin_amdgcn_mfma_f32_16x16x32_f16(alo[qt][1], bhi1, cacc, 0, 0, 0); \
      cacc = __builtin_amdgcn_mfma_f32_16x16x32_f16(ahi[qt][0], blo0, cacc, 0, 0, 0); \
      cacc = __builtin_amdgcn_mfma_f32_16x16x32_f16(ahi[qt][1], blo1, cacc, 0, 0, 0); \
      cacc = __builtin_amdgcn_mfma_f32_16x16x32_f16(ahi[qt][0], bhi0, cacc, 0, 0, 0); \
      cacc = __builtin_amdgcn_mfma_f32_16x16x32_f16(ahi[qt][1], bhi1, cacc, 0, 0, 0); \
      _Pragma("unroll")                                                         \
      for (int rp = 0; rp < 2; ++rp) {                                          \
        f32x2 rr = { cacc[2 * rp], cacc[2 * rp + 1] };                          \
        f32x2 sc = rr * C1;                    /* v_pk_mul_f32 */               \
        f32x2 e  = { EXP2F(sc[0]), EXP2F(sc[1]) };                              \
        l32[qt][rp] += e;                      /* v_pk_add_f32 */               \
        t32[qt][rp] += rr * e;                 /* v_pk_fma_f32 */               \
      }                                                                         \
    }                                                                           \
  }

  // prologue: stage sub-chunk 0 into A
  GL2LDS16(gp, ldsA);
  GL2LDS16(gp + 8192, ldsA + 4096);
  __syncthreads();

  for (int j = 0; j < 16; ++j) {
    // stage sub-chunk 2j+1 into B (overlaps compute of A)
    GL2LDS16(gp + 4096, ldsB);
    GL2LDS16(gp + 12288, ldsB + 4096);

    f32x2 l32[2][2], t32[2][2];
#pragma unroll
    for (int qt = 0; qt < 2; ++qt)
#pragma unroll
      for (int rp = 0; rp < 2; ++rp) {
        l32[qt][rp] = (f32x2){0.f, 0.f};
        t32[qt][rp] = (f32x2){0.f, 0.f};
      }

    KLSTEP(khiA, kloA)
    __syncthreads();              // B ready (drain hidden under A compute); A free

    if (j < 15) {
      gp += 16384;                // next pair base
      GL2LDS16(gp, ldsA);         // stage sub-chunk 2j+2 into A (overlaps B compute)
      GL2LDS16(gp + 8192, ldsA + 4096);
    }

    KLSTEP(khiB, kloB)

    // fold every 64 keys (identical cadence/numerics to r10)
#pragma unroll
    for (int qt = 0; qt < 2; ++qt)
#pragma unroll
      for (int rp = 0; rp < 2; ++rp)
#pragma unroll
        for (int c = 0; c < 2; ++c) {
          l64[qt][rp * 2 + c] += (double)l32[qt][rp][c];
          t64[qt][rp * 2 + c] += (double)t32[qt][rp][c];
        }
    __syncthreads();              // A ready for next j; B free
  }
#undef KLSTEP

#pragma unroll
  for (int qt = 0; qt < 2; ++qt)
#pragma unroll
    for (int r = 0; r < 4; ++r) {
      double lv = l64[qt][r], tv = t64[qt][r];
#pragma unroll
      for (int m = 1; m < 16; m <<= 1) {
        lv += __shfl_xor(lv, m);
        tv += __shfl_xor(tv, m);
      }
      if (l15 == 0) {
        int qg = qc * 128 + w * 32 + qt * 16 + quad * 4 + r;
        double* dst = lt + ((size_t)(sp * 64 + bh) * LQ + qg) * 2;
        dst[0] = lv;
        dst[1] = tv;
      }
    }
}

// ---------------------------------------------------------------------------
// topk2 r13: register top-3 per lane kills the per-round serial LDS rescan.
// Old: every round the owner lane rescanned its 32 LDS slots (~120cyc
// latency each, exec-masked single lane) => ~60us of pure serial latency at
// 64 waves on the whole GPU. New invariant: the global winner is ALWAYS the
// owner's register b1 (butterfly maxes over lanes' b1), so a kill is a
// register shift b1<-b2<-b3. Full rescan only when a lane's 3 slots are
// exhausted (Poisson(0.6) tail, ~1-2x/block). vals[] stays truthful (-inf at
// kills) so rescans are exact. Compare values, tie rules (strict >, lowest
// index), and selection order are bit-identical to the validated version.
// ---------------------------------------------------------------------------
__global__ __launch_bounds__(64) void topk2(const double* __restrict__ lt,
                                            int* __restrict__ idxout,
                                            signed char* __restrict__ selmask) {
  int bh = blockIdx.x;
  int lane = threadIdx.x;
  __shared__ double vals[LQ];
  const double logL = 7.624618986159398;

  double v1 = -INFINITY, v2 = -INFINITY, v3 = -INFINITY;
  int i1 = LQ, i2 = LQ, i3 = LQ;

  for (int j = 0; j < 32; ++j) {
    int i = j * 64 + lane;
    const double* p0 = lt + ((size_t)bh * LQ + i) * 2;
    const double* p1 = lt + ((size_t)(64 + bh) * LQ + i) * 2;
    double l = p0[0] + p1[0];
    double tt = p0[1] + p1[1];
    double v = 0.125 * (tt / l) - log(l) + logL;
    vals[i] = v;
    selmask[bh * LQ + i] = -1;
    // ascending-i scan + strict > == lowest-index-wins on ties (matches old)
    if (v > v1)      { v3 = v2; i3 = i2; v2 = v1; i2 = i1; v1 = v; i1 = i; }
    else if (v > v2) { v3 = v2; i3 = i2; v2 = v;  i2 = i; }
    else if (v > v3) { v3 = v;  i3 = i; }
  }

  for (int u = 0; u < UU; ++u) {
    if (i1 == LQ) {
      // register slots exhausted: exact rebuild from truthful vals[]
      v1 = v2 = v3 = -INFINITY;
      i1 = i2 = i3 = LQ;
      for (int j = 0; j < 32; ++j) {
        int i = j * 64 + lane;
        double v = vals[i];
        if (v > v1)      { v3 = v2; i3 = i2; v2 = v1; i2 = i1; v1 = v; i1 = i; }
        else if (v > v2) { v3 = v2; i3 = i2; v2 = v;  i2 = i; }
        else if (v > v3) { v3 = v;  i3 = i; }
      }
    }

    double gv = v1;
    int gi = i1;
#pragma unroll
    for (int m = 1; m < 64; m <<= 1) {
      double ov = __shfl_xor(gv, m);
      int oi = __shfl_xor(gi, m);
      if (ov > gv || (ov == gv && oi < gi)) { gv = ov; gi = oi; }
    }
    if (lane == 0) {
      idxout[bh * UU + u] = gi;
      selmask[bh * LQ + gi] = (signed char)u;
    }
    if ((gi & 63) == lane) {
      // winner is exactly this lane's b1 (it was the contributed candidate)
      vals[gi] = -INFINITY;          // keep LDS truthful for future rescans
      v1 = v2; i1 = i2;
      v2 = v3; i2 = i3;
      v3 = -INFINITY; i3 = LQ;
    }
  }
}

// ---------------------------------------------------------------------------
// attn_w_mfma: unchanged from r10 (DMA staging, unnormalized wout).
// ---------------------------------------------------------------------------
__global__ __launch_bounds__(256) void attn_w_mfma(const float* __restrict__ Q,
                                                   const _Float16* __restrict__ ksp,
                                                   const int* __restrict__ sel,
                                                   float* __restrict__ wout,
                                                   float* __restrict__ lpart) {
  int bh = blockIdx.x >> 4;
  int ks = blockIdx.x & 15;
  int b = bh >> 4, h = bh & 15;
  int t = threadIdx.x;
  int lane = t & 63, w = t >> 6;
  int quad = lane >> 4, l15 = lane & 15;

  __shared__ __align__(16) _Float16 kbuf[8192];   // 16 KB chunk image
  __shared__ float els[48 * 132];                 // 25.3 KB
  __shared__ int sidx[UU];

  if (t < UU) sidx[t] = sel[bh * UU + t];
  __syncthreads();

  f16x8 ahi[3][2], alo[3][2];
#pragma unroll
  for (int qt = 0; qt < 3; ++qt) {
    int u = qt * 16 + l15;
    if (u > 37) u = 37;                           // duplicate row 37 for pads
    const float* qrow = Q + ((size_t)(b * LQ + sidx[u])) * DM + h * DH;
#pragma unroll
    for (int c = 0; c < 2; ++c) {
      const float* p = qrow + c * 32 + quad * 8;
      float4 x0 = *(const float4*)p;
      float4 x1 = *(const float4*)(p + 4);
      f16x8 hi, lo;
#define QCV(i, xx) { float x_ = (xx); _Float16 hh = (_Float16)x_; hi[i] = hh; lo[i] = (_Float16)(x_ - (float)hh); }
      QCV(0, x0.x) QCV(1, x0.y) QCV(2, x0.z) QCV(3, x0.w)
      QCV(4, x1.x) QCV(5, x1.y) QCV(6, x1.z) QCV(7, x1.w)
#undef QCV
      ahi[qt][c] = hi;
      alo[qt][c] = lo;
    }
  }

  int bsw0 = quad ^ (l15 & 7);
  int bsw1 = (quad + 4) ^ (l15 & 7);
  const float C1 = 0.18033688011112042f;
  const char* gch = (const char*)(ksp + ((size_t)(bh * 32 + ks * 2)) * 8192);
  _Float16* khi = kbuf;
  _Float16* klo = kbuf + 4096;

  for (int chunk = 0; chunk < 2; ++chunk) {
    __syncthreads();
    {
      const char* gs = gch + (size_t)chunk * 16384 + (size_t)t * 16;
      char* ls = (char*)kbuf + (size_t)(w * 64) * 16;
#pragma unroll
      for (int i = 0; i < 4; ++i)
        GL2LDS16(gs + i * 4096, ls + i * 4096);
    }
    __syncthreads();
    int key = w * 16 + l15;
    f16x8 bhi0 = *(const f16x8*)(khi + key * 64 + bsw0 * 8);
    f16x8 bhi1 = *(const f16x8*)(khi + key * 64 + bsw1 * 8);
    f16x8 blo0 = *(const f16x8*)(klo + key * 64 + bsw0 * 8);
    f16x8 blo1 = *(const f16x8*)(klo + key * 64 + bsw1 * 8);
#pragma unroll
    for (int qt = 0; qt < 3; ++qt) {
      f32x4 cacc = {0.f, 0.f, 0.f, 0.f};
      cacc = __builtin_amdgcn_mfma_f32_16x16x32_f16(alo[qt][0], bhi0, cacc, 0, 0, 0);
      cacc = __builtin_amdgcn_mfma_f32_16x16x32_f16(alo[qt][1], bhi1, cacc, 0, 0, 0);
      cacc = __builtin_amdgcn_mfma_f32_16x16x32_f16(ahi[qt][0], blo0, cacc, 0, 0, 0);
      cacc = __builtin_amdgcn_mfma_f32_16x16x32_f16(ahi[qt][1], blo1, cacc, 0, 0, 0);
      cacc = __builtin_amdgcn_mfma_f32_16x16x32_f16(ahi[qt][0], bhi0, cacc, 0, 0, 0);
      cacc = __builtin_amdgcn_mfma_f32_16x16x32_f16(ahi[qt][1], bhi1, cacc, 0, 0, 0);
#pragma unroll
      for (int r = 0; r < 4; ++r) {
        float e = EXP2F(cacc[r] * C1);
        els[(qt * 16 + quad * 4 + r) * 132 + chunk * 64 + w * 16 + l15] = e;
      }
    }
  }
  __syncthreads();

  // coalesced dump (rows 38-47 never touched)
  for (int i = t; i < UU * 128; i += 256) {
    int u = i >> 7, k = i & 127;
    wout[((size_t)(bh * UU + u)) * LQ + ks * 128 + k] = els[u * 132 + k];
  }

  // row sums -> lpart: wave w reduces rows u = w + 4p
#pragma unroll
  for (int p = 0; p < 10; ++p) {
    int u = w + 4 * p;
    if (u < UU) {
      float s = els[u * 132 + lane] + els[u * 132 + 64 + lane];
#pragma unroll
      for (int m = 1; m < 64; m <<= 1) s += __shfl_xor(s, m);
      if (lane == 0) lpart[(bh * 16 + ks) * UU + u] = s;
    }
  }
}

// ---------------------------------------------------------------------------
// attn_pv2: unchanged from r9 (normalization fused here; opart pre-normalized).
// ---------------------------------------------------------------------------
__global__ __launch_bounds__(256) void attn_pv2(const float* __restrict__ V,
                                                float* __restrict__ wout,
                                                const float* __restrict__ lpart,
                                                float* __restrict__ opart) {
  int bh = blockIdx.x >> 4;
  int ks = blockIdx.x & 15;
  int b = bh >> 4, h = bh & 15;
  int t = threadIdx.x;
  int d = t & 63, ug = t >> 6;

  __shared__ float ps[40 * 132];   // rows 38,39 zeroed (pad accumulators)
  __shared__ float l3s[UU];        // 1 / full row sum

  if (t < UU) {
    float s = 0.f;
#pragma unroll
    for (int i = 0; i < 16; ++i) s += lpart[(bh * 16 + i) * UU + t];
    l3s[t] = 1.f / s;
  }
  for (int i = t; i < 2 * 132; i += 256) ps[UU * 132 + i] = 0.f;
  __syncthreads();

  for (int i = t; i < UU * 32; i += 256) {
    int u = i >> 5, d4 = i & 31;
    float r = l3s[u];
    float* wp = wout + ((size_t)(bh * UU + u)) * LQ + ks * 128 + d4 * 4;
    float4 v = *(const float4*)wp;
    v.x *= r; v.y *= r; v.z *= r; v.w *= r;
    *(float4*)(ps + u * 132 + d4 * 4) = v;
    *(float4*)wp = v;                 // wout now final (normalized weights)
  }
  __syncthreads();

  const float* vbase = V + ((size_t)(b * LQ + ks * 128)) * DM + h * DH + d;
  float o[10];
#pragma unroll
  for (int p = 0; p < 10; ++p) o[p] = 0.f;

  for (int j4 = 0; j4 < 128; j4 += 4) {
    float v0 = vbase[(size_t)(j4 + 0) * DM];
    float v1 = vbase[(size_t)(j4 + 1) * DM];
    float v2 = vbase[(size_t)(j4 + 2) * DM];
    float v3 = vbase[(size_t)(j4 + 3) * DM];
#pragma unroll
    for (int p = 0; p < 10; ++p) {
      float4 pw = *(const float4*)(ps + (ug + 4 * p) * 132 + j4);
      o[p] = fmaf(pw.x, v0, o[p]);
      o[p] = fmaf(pw.y, v1, o[p]);
      o[p] = fmaf(pw.z, v2, o[p]);
      o[p] = fmaf(pw.w, v3, o[p]);
    }
  }

#pragma unroll
  for (int p = 0; p < 10; ++p) {
    int u = ug + 4 * p;
    if (u < UU) opart[((size_t)((bh * 16 + ks) * UU + u)) * DH + d] = o[p];
  }
}

// ---------------------------------------------------------------------------
// writeout: unchanged from r9 -- dense-output pass only.
// ---------------------------------------------------------------------------
__global__ __launch_bounds__(256) void writeout_kernel(const signed char* __restrict__ selmask,
                                                       const float* __restrict__ opart,
                                                       float* __restrict__ out) {
  int i2 = blockIdx.x * 256 + threadIdx.x;   // < 8,388,608 (exact grid)
  int d = i2 & 63;
  int h = (i2 >> 6) & 15;
  int q = (i2 >> 10) & 2047;
  int b = i2 >> 21;
  int bh = b * 16 + h;
  int u = selmask[bh * LQ + q];
  float val = 0.f;
  if (u >= 0) {
    float s = 0.f;
#pragma unroll
    for (int p = 0; p < 16; ++p)
      s += opart[((size_t)((bh * 16 + p) * UU + u)) * DH + d];
    val = s;
  }
  out[i2] = val;
}

extern "C" void kernel_launch(void* const* d_in, const int* in_sizes, int n_in,
                              void* d_out, int out_size, void* d_ws, size_t ws_size,
                              hipStream_t stream) {
  (void)in_sizes; (void)n_in;
  if (ws_size < F_NEED) return;   // fail visibly (poisoned out) over UB; r8 confirmed fit
  const float* Q = (const float*)d_in[0];
  const float* K = (const float*)d_in[1];
  const float* V = (const float*)d_in[2];
  float* out = (float*)d_out;
  float* wout = out + (size_t)4 * LQ * DM;
  char* ws = (char*)d_ws;

  double* lt = (double*)ws;
  int* sel = (int*)(ws + F_OFF_SEL);
  signed char* mask = (signed char*)(ws + F_OFF_MASK);
  float* lpart = (float*)(ws + F_OFF_LPART);
  _Float16* ksp = (_Float16*)(ws + F_OFF_KSP);
  float* opart = (float*)(ws + F_OFF_KSP);   // aliases ksp, stream-ordered safe

  ksplit_kernel<<<4096, 256, 0, stream>>>(K, ksp);
  kl_mfma2<<<2048, 256, 0, stream>>>(Q, ksp, lt);
  topk2<<<NBH, 64, 0, stream>>>(lt, sel, mask);
  attn_w_mfma<<<NBH * 16, 256, 0, stream>>>(Q, ksp, sel, wout, lpart);
  attn_pv2<<<NBH * 16, 256, 0, stream>>>(V, wout, lpart, opart);
  writeout_kernel<<<(4 * LQ * DM) / 256, 256, 0, stream>>>(mask, opart, out);
}